// Round 5
// baseline (751.250 us; speedup 1.0000x reference)
//
#include <hip/hip_runtime.h>
#include <hip/hip_bf16.h>

// Problem constants (from reference)
#define NN 20000
#define EE 320000
#define FF 75
#define GG 64
#define LL 5
#define EPS 1e-5f

// GEMM paddings
#define KUV 96      // K for uv gemm (h: 75 -> 96; col 75 = 1.0 bias trick)
#define NUV 160     // cols: u at 0..74, v at 80..154
#define KPOST 384   // K for post gemm ([h|agg]: 375 -> 384)
#define NPOST 240   // cols: block0 0..74, block1 80..154, block2 160..234
#define KLIN 96

typedef short bf16x8 __attribute__((ext_vector_type(8)));
typedef float f32x4 __attribute__((ext_vector_type(4)));

__device__ inline void gAtomicAdd(float* p, float v) { unsafeAtomicAdd(p, v); }

__device__ inline ushort f2bs(float x) {
    __hip_bfloat16 b = __float2bfloat16(x);
    return *(ushort*)&b;
}

__device__ inline float bs2f(ushort u) {
    unsigned int x = ((unsigned int)u) << 16;
    return __uint_as_float(x);
}

// ---------------- CSR construction ----------------

__global__ void count_kernel(const int* __restrict__ col, int* __restrict__ cnt, int E) {
    int e = blockIdx.x * blockDim.x + threadIdx.x;
    if (e < E) atomicAdd(&cnt[col[e]], 1);
}

__global__ void partial_kernel(const int* __restrict__ cnt, int* __restrict__ bsum, int N) {
    __shared__ int sh[256];
    int tid = threadIdx.x;
    int i = blockIdx.x * 256 + tid;
    sh[tid] = (i < N) ? cnt[i] : 0;
    __syncthreads();
    for (int s = 128; s > 0; s >>= 1) {
        if (tid < s) sh[tid] += sh[tid + s];
        __syncthreads();
    }
    if (tid == 0) bsum[blockIdx.x] = sh[0];
}

__global__ void scanb_kernel(const int* __restrict__ bsum, int* __restrict__ bbase,
                             int* __restrict__ offs, int NB) {
    __shared__ int sh[128];
    int tid = threadIdx.x;
    int v = (tid < NB) ? bsum[tid] : 0;
    sh[tid] = v;
    __syncthreads();
    for (int d = 1; d < 128; d <<= 1) {
        int t = (tid >= d) ? sh[tid - d] : 0;
        __syncthreads();
        sh[tid] += t;
        __syncthreads();
    }
    if (tid < NB) bbase[tid] = sh[tid] - v;
    if (tid == 0) offs[NN] = EE;
}

__global__ void offs_kernel(const int* __restrict__ cnt, const int* __restrict__ bbase,
                            int* __restrict__ offs, int* __restrict__ cursor, int N) {
    __shared__ int sh[256];
    int tid = threadIdx.x;
    int i = blockIdx.x * 256 + tid;
    int v = (i < N) ? cnt[i] : 0;
    sh[tid] = v;
    __syncthreads();
    for (int d = 1; d < 256; d <<= 1) {
        int t = (tid >= d) ? sh[tid - d] : 0;
        __syncthreads();
        sh[tid] += t;
        __syncthreads();
    }
    int excl = sh[tid] - v + bbase[blockIdx.x];
    if (i < N) { offs[i] = excl; cursor[i] = excl; }
}

__global__ void fill_kernel(const int* __restrict__ row, const int* __restrict__ col,
                            int* __restrict__ cursor, int* __restrict__ csr, int E) {
    int e = blockIdx.x * blockDim.x + threadIdx.x;
    if (e < E) {
        int c = col[e];
        int pos = atomicAdd(&cursor[c], 1);
        csr[pos] = row[e];
    }
}

// ---------------- degree-derived quantities ----------------

__global__ void dinv_kernel(const int* __restrict__ cnt, float* __restrict__ dinv,
                            float* __restrict__ scal, int N) {
    __shared__ float red[256];
    int i = blockIdx.x * 256 + threadIdx.x;
    float lg = 0.f;
    if (i < N) {
        float c = (float)cnt[i];
        dinv[i] = 1.f / sqrtf(c + 1.f);
        lg = logf(c + 1.f);
    }
    red[threadIdx.x] = lg;
    __syncthreads();
    for (int s = 128; s > 0; s >>= 1) {
        if (threadIdx.x < s) red[threadIdx.x] += red[threadIdx.x + s];
        __syncthreads();
    }
    if (threadIdx.x == 0) gAtomicAdd(&scal[0], red[0]);
}

// ---------------- GCN ----------------

__global__ void xw_kernel(const float* __restrict__ x, const float* __restrict__ gw,
                          float* __restrict__ xw, int N) {
    int idx = blockIdx.x * 256 + threadIdx.x;
    if (idx >= N * FF) return;
    int n = idx / FF, f = idx % FF;
    float acc = 0.f;
#pragma unroll
    for (int k = 0; k < 6; k++) acc += x[n * 6 + k] * gw[k * FF + f];
    xw[idx] = acc;
}

// writes h (fp32), hb (bf16 [N,96], col75=1.0 bias trick), hagg cols 0..74 + pad
__global__ void gcn_kernel(const float* __restrict__ xw, const float* __restrict__ dinv,
                           const int* __restrict__ offs, const int* __restrict__ csr,
                           const float* __restrict__ gcn_b, const int* __restrict__ cnt,
                           const float* __restrict__ scal,
                           float* __restrict__ h, ushort* __restrict__ hb,
                           ushort* __restrict__ hagg,
                           float* __restrict__ amp, float* __restrict__ att, int N) {
    int i = blockIdx.x;
    int t = threadIdx.x;  // blockDim = 96
    int s0 = offs[i], s1 = offs[i + 1];
    float di = dinv[i];
    if (t < FF) {
        float acc = 0.f;
        for (int k = s0; k < s1; k++) {
            int r = csr[k];
            acc += dinv[r] * xw[r * FF + t];
        }
        float val = di * acc + di * di * xw[i * FF + t] + gcn_b[t];
        h[i * FF + t] = val;
        hb[i * KUV + t] = f2bs(val);
        hagg[(size_t)i * KPOST + t] = f2bs(val);
    } else {
        hb[i * KUV + t] = f2bs(t == FF ? 1.f : 0.f);  // col75 = 1 for bias fold
        if (t >= 87) hagg[(size_t)i * KPOST + 375 + (t - 87)] = 0;
    }
    if (t == 0) {
        float al = scal[0] / (float)N;
        float d = fmaxf((float)cnt[i], 1.f);
        float lg = logf(d + 1.f);
        amp[i] = lg / al;
        att[i] = al / lg;
    }
}

// ---------------- B-matrix prep (bf16, transposed: BT[col][k]) ----------------

#define S_UV (LL * NUV * KUV)
#define S_POST (LL * NPOST * KPOST)
#define S_LIN (LL * NUV / 2 * KLIN)  // 80*96 per layer

__global__ void prep_bt_kernel(const float* __restrict__ pre_w, const float* __restrict__ pre_b,
                               const float* __restrict__ post_w, const float* __restrict__ lin_w,
                               ushort* __restrict__ BTuv, ushort* __restrict__ BTpost,
                               ushort* __restrict__ BTlin) {
    int idx = blockIdx.x * 256 + threadIdx.x;
    if (idx < S_UV) {
        int l = idx / (NUV * KUV);
        int r = idx % (NUV * KUV);
        int c = r / KUV, k = r % KUV;
        float v = 0.f;
        if (k < FF) {
            if (c < FF) v = pre_w[((size_t)l * 150 + k) * FF + c];
            else if (c >= 80 && c < 80 + FF) v = pre_w[((size_t)l * 150 + FF + k) * FF + (c - 80)];
        } else if (k == FF && c < FF) {
            v = pre_b[l * FF + c];  // bias fold: A col75 = 1.0
        }
        BTuv[idx] = f2bs(v);
    } else if (idx < S_UV + S_POST) {
        int j = idx - S_UV;
        int l = j / (NPOST * KPOST);
        int r = j % (NPOST * KPOST);
        int c = r / KPOST, k = r % KPOST;
        float v = 0.f;
        if (k < FF) {
            if (c < FF) v = post_w[((size_t)l * 975 + k) * FF + c];
        } else if (k < 375) {
            if (c < FF) v = post_w[((size_t)l * 975 + k) * FF + c];
            else if (c >= 80 && c < 80 + FF) v = post_w[((size_t)l * 975 + k + 300) * FF + (c - 80)];
            else if (c >= 160 && c < 160 + FF) v = post_w[((size_t)l * 975 + k + 600) * FF + (c - 160)];
        }
        BTpost[j] = f2bs(v);
    } else if (idx < S_UV + S_POST + S_LIN) {
        int j = idx - S_UV - S_POST;
        int l = j / (80 * KLIN);
        int r = j % (80 * KLIN);
        int c = r / KLIN, k = r % KLIN;
        float v = (c < FF && k < FF) ? lin_w[((size_t)l * FF + k) * FF + c] : 0.f;
        BTlin[j] = f2bs(v);
    }
}

// ---------------- uv GEMM, N-split: gy=0 -> U (fp32), gy=1 -> V (bf16) ----------------

__global__ __launch_bounds__(256) void gemm_uv_kernel(const ushort* __restrict__ A,
                                                      const ushort* __restrict__ BT,
                                                      float* __restrict__ U,
                                                      ushort* __restrict__ Vb, int M) {
    constexpr int NROWS = 64 + 80;   // A rows + 5 B tiles
    constexpr int SEGS = NROWS * 4;  // 576
    constexpr int BUF = NROWS * 40;
    __shared__ __align__(16) ushort sh[2 * BUF];
    int tid = threadIdx.x, w = tid >> 6, lane = tid & 63;
    int col16 = lane & 15, quad = lane >> 4, kseg = quad * 8;
    int n0 = blockIdx.x * 64;
    int g = blockIdx.y;  // 0 = u cols, 1 = v cols
    const ushort* BTg = BT + (size_t)g * 80 * KUV;

    f32x4 acc[5];
#pragma unroll
    for (int i = 0; i < 5; i++) acc[i] = (f32x4){0.f, 0.f, 0.f, 0.f};

    uint4 pf[3];
    auto loadk = [&](int kt) {
#pragma unroll
        for (int i = 0; i < 3; i++) {
            int s = tid + i * 256;
            if (s < SEGS) {
                int r = s >> 2, sg = s & 3;
                const ushort* src;
                if (r < 64) {
                    int n = min(n0 + r, M - 1);
                    src = A + (size_t)n * KUV + kt * 32 + sg * 8;
                } else {
                    src = BTg + (size_t)(r - 64) * KUV + kt * 32 + sg * 8;
                }
                pf[i] = *(const uint4*)src;
            }
        }
    };
    auto storek = [&](ushort* buf) {
#pragma unroll
        for (int i = 0; i < 3; i++) {
            int s = tid + i * 256;
            if (s < SEGS) {
                int r = s >> 2, sg = s & 3;
                *(uint4*)(buf + r * 40 + sg * 8) = pf[i];
            }
        }
    };
    loadk(0);
    storek(sh);
    for (int kt = 0; kt < 3; kt++) {
        __syncthreads();
        const ushort* cur = sh + (kt & 1) * BUF;
        if (kt < 2) loadk(kt + 1);
        bf16x8 af = *(const bf16x8*)(cur + (w * 16 + col16) * 40 + kseg);
#pragma unroll
        for (int nt = 0; nt < 5; nt++) {
            bf16x8 bfr = *(const bf16x8*)(cur + (64 + nt * 16 + col16) * 40 + kseg);
            acc[nt] = __builtin_amdgcn_mfma_f32_16x16x32_bf16(af, bfr, acc[nt], 0, 0, 0);
        }
        if (kt < 2) storek(sh + ((kt + 1) & 1) * BUF);
    }
#pragma unroll
    for (int nt = 0; nt < 5; nt++) {
        int col = nt * 16 + col16;
#pragma unroll
        for (int r = 0; r < 4; r++) {
            int n = n0 + w * 16 + quad * 4 + r;
            if (n < M && col < FF) {
                if (g == 0) U[(size_t)n * 80 + col] = acc[nt][r];
                else Vb[(size_t)n * 80 + col] = f2bs(acc[nt][r]);
            }
        }
    }
}

// ---------------- post GEMM, N-split into 5 groups; combine in epilogue ----------------
// group g computes tiles g, g+5, g+10 and writes o[:, g*16 .. g*16+15] (bf16) to obuf [N,80]

__global__ __launch_bounds__(256) void post_group_kernel(
    const ushort* __restrict__ A, const ushort* __restrict__ BT,
    const float* __restrict__ amp, const float* __restrict__ att,
    ushort* __restrict__ obuf, int M) {
    constexpr int NROWS = 64 + 48;   // A rows + 3 B tiles
    constexpr int SEGS = NROWS * 4;  // 448
    constexpr int BUF = NROWS * 40;
    __shared__ __align__(16) ushort sh[2 * BUF];  // 17920 B
    int tid = threadIdx.x, w = tid >> 6, lane = tid & 63;
    int col16 = lane & 15, quad = lane >> 4, kseg = quad * 8;
    int n0 = blockIdx.x * 64;
    int g = blockIdx.y;

    f32x4 acc[3];
#pragma unroll
    for (int i = 0; i < 3; i++) acc[i] = (f32x4){0.f, 0.f, 0.f, 0.f};

    uint4 pf[2];
    auto loadk = [&](int kt) {
#pragma unroll
        for (int i = 0; i < 2; i++) {
            int s = tid + i * 256;
            if (s < SEGS) {
                int r = s >> 2, sg = s & 3;
                const ushort* src;
                if (r < 64) {
                    int n = min(n0 + r, M - 1);
                    src = A + (size_t)n * KPOST + kt * 32 + sg * 8;
                } else {
                    int lb = r - 64;
                    int grow = (g + 5 * (lb >> 4)) * 16 + (lb & 15);
                    src = BT + (size_t)grow * KPOST + kt * 32 + sg * 8;
                }
                pf[i] = *(const uint4*)src;
            }
        }
    };
    auto storek = [&](ushort* buf) {
#pragma unroll
        for (int i = 0; i < 2; i++) {
            int s = tid + i * 256;
            if (s < SEGS) {
                int r = s >> 2, sg = s & 3;
                *(uint4*)(buf + r * 40 + sg * 8) = pf[i];
            }
        }
    };
    loadk(0);
    storek(sh);
    for (int kt = 0; kt < 12; kt++) {
        __syncthreads();
        const ushort* cur = sh + (kt & 1) * BUF;
        if (kt < 11) loadk(kt + 1);
        bf16x8 af = *(const bf16x8*)(cur + (w * 16 + col16) * 40 + kseg);
#pragma unroll
        for (int nt = 0; nt < 3; nt++) {
            bf16x8 bfr = *(const bf16x8*)(cur + (64 + nt * 16 + col16) * 40 + kseg);
            acc[nt] = __builtin_amdgcn_mfma_f32_16x16x32_bf16(af, bfr, acc[nt], 0, 0, 0);
        }
        if (kt < 11) storek(sh + ((kt + 1) & 1) * BUF);
    }
    // epilogue: combine with amp/att, write o bf16
    int col = g * 16 + col16;  // 0..79
#pragma unroll
    for (int r = 0; r < 4; r++) {
        int n = n0 + w * 16 + quad * 4 + r;
        if (n < M) {
            float a = amp[n], t = att[n];
            float ov = acc[0][r] + a * acc[1][r] + t * acc[2][r];
            obuf[(size_t)n * 80 + col] = (col < FF) ? f2bs(ov) : (ushort)0;
        }
    }
}

// ---------------- lin GEMM + BN stats (single-shot staging, K=96) ----------------

__global__ __launch_bounds__(256) void lin_bn_kernel(
    const ushort* __restrict__ obuf, const ushort* __restrict__ BL,
    float* __restrict__ o2, float* __restrict__ bnsum, float* __restrict__ bnssq, int M) {
    constexpr int LR = 104;  // row stride (208 B)
    __shared__ __align__(16) ushort sh[(64 + 80) * LR];  // A rows 0..63, B rows 64..143
    __shared__ float bns[80], bnq[80];
    int tid = threadIdx.x, w = tid >> 6, lane = tid & 63;
    int col16 = lane & 15, quad = lane >> 4, kseg = quad * 8;
    int n0 = blockIdx.x * 64;
    if (tid < 80) { bns[tid] = 0.f; bnq[tid] = 0.f; }

    // stage A: 64 rows x 12 segs (10 data from obuf, 2 zero pad)
    for (int s = tid; s < 768; s += 256) {
        int r = s / 12, sg = s % 12;
        uint4 v = {0u, 0u, 0u, 0u};
        if (sg < 10) {
            int n = min(n0 + r, M - 1);
            v = *(const uint4*)(obuf + (size_t)n * 80 + sg * 8);
        }
        *(uint4*)(sh + r * LR + sg * 8) = v;
    }
    // stage B: 80 rows x 12 segs
    for (int s = tid; s < 960; s += 256) {
        int r = s / 12, sg = s % 12;
        *(uint4*)(sh + (64 + r) * LR + sg * 8) = *(const uint4*)(BL + r * 96 + sg * 8);
    }
    __syncthreads();

    f32x4 acc[5];
#pragma unroll
    for (int i = 0; i < 5; i++) acc[i] = (f32x4){0.f, 0.f, 0.f, 0.f};
#pragma unroll
    for (int kt = 0; kt < 3; kt++) {
        bf16x8 af = *(const bf16x8*)(sh + (w * 16 + col16) * LR + kt * 32 + kseg);
#pragma unroll
        for (int nt = 0; nt < 5; nt++) {
            bf16x8 bfr = *(const bf16x8*)(sh + (64 + nt * 16 + col16) * LR + kt * 32 + kseg);
            acc[nt] = __builtin_amdgcn_mfma_f32_16x16x32_bf16(af, bfr, acc[nt], 0, 0, 0);
        }
    }
    // epilogue: store o2 + BN partial sums
#pragma unroll
    for (int nt = 0; nt < 5; nt++) {
        int col = nt * 16 + col16;
        float s = 0.f, q = 0.f;
#pragma unroll
        for (int r = 0; r < 4; r++) {
            int n = n0 + w * 16 + quad * 4 + r;
            float v = acc[nt][r];
            if (n < M && col < FF) {
                o2[(size_t)n * 80 + col] = v;
                s += v;
                q += v * v;
            }
        }
        s += __shfl_xor(s, 16); s += __shfl_xor(s, 32);
        q += __shfl_xor(q, 16); q += __shfl_xor(q, 32);
        if (lane < 16 && col < FF) {
            atomicAdd(&bns[col], s);
            atomicAdd(&bnq[col], q);
        }
    }
    __syncthreads();
    if (tid < FF) {
        gAtomicAdd(&bnsum[tid], bns[tid]);
        gAtomicAdd(&bnssq[tid], bnq[tid]);
    }
}

// ---------------- per-layer helper kernels ----------------

// aggregation over edges; u fp32 [N,80], v bf16 [N,80]
__global__ void edge_agg_kernel(const float* __restrict__ U, const ushort* __restrict__ V,
                                const int* __restrict__ offs, const int* __restrict__ csr,
                                const int* __restrict__ cnt,
                                ushort* __restrict__ hagg, int N) {
    int i = blockIdx.x;
    int t = threadIdx.x;
    if (t >= FF) return;
    int s0 = offs[i], s1 = offs[i + 1];
    float ui = U[(size_t)i * 80 + t];
    float s = 0.f, ss = 0.f, mn = 1e30f, mx = -1e30f;
    int k = s0;
    for (; k + 1 < s1; k += 2) {
        int r0 = csr[k], r1 = csr[k + 1];
        float m0 = ui + bs2f(V[(size_t)r0 * 80 + t]);
        float m1 = ui + bs2f(V[(size_t)r1 * 80 + t]);
        s += m0 + m1;
        ss += m0 * m0 + m1 * m1;
        mn = fminf(mn, fminf(m0, m1));
        mx = fmaxf(mx, fmaxf(m0, m1));
    }
    if (k < s1) {
        int r0 = csr[k];
        float m0 = ui + bs2f(V[(size_t)r0 * 80 + t]);
        s += m0;
        ss += m0 * m0;
        mn = fminf(mn, m0);
        mx = fmaxf(mx, m0);
    }
    int c = cnt[i];
    float cc = fmaxf((float)c, 1.f);
    float mean = s / cc;
    float msq = ss / cc;
    float stdv = sqrtf(fmaxf(msq - mean * mean, 0.f) + EPS);
    if (c == 0) { mn = 0.f; mx = 0.f; }
    ushort* a = hagg + (size_t)i * KPOST + FF;
    a[t] = f2bs(mean);
    a[FF + t] = f2bs(mn);
    a[2 * FF + t] = f2bs(mx);
    a[3 * FF + t] = f2bs(stdv);
}

// BN + ReLU; writes h (fp32), hb (bf16), hagg cols 0..74 (bf16)
__global__ void bn_kernel(const float* __restrict__ o2, const float* __restrict__ bnsum,
                          const float* __restrict__ bnssq, const float* __restrict__ bg,
                          const float* __restrict__ bb, float* __restrict__ h,
                          ushort* __restrict__ hb, ushort* __restrict__ hagg, int N) {
    int idx = blockIdx.x * 256 + threadIdx.x;
    if (idx >= N * FF) return;
    int n = idx / FF, c = idx % FF;
    float mu = bnsum[c] * (1.f / (float)N);
    float var = bnssq[c] * (1.f / (float)N) - mu * mu;
    float val = (o2[(size_t)n * 80 + c] - mu) * rsqrtf(var + EPS) * bg[c] + bb[c];
    val = fmaxf(val, 0.f);
    h[idx] = val;
    hb[n * KUV + c] = f2bs(val);
    hagg[(size_t)n * KPOST + c] = f2bs(val);
}

// ---------------- pooling + final MLP ----------------

__global__ void pool_kernel(const float* __restrict__ h, const int* __restrict__ batch,
                            float* __restrict__ g, int N) {
    __shared__ float acc[GG * FF];
    int n0 = blockIdx.x * 64;
    int n1 = min(n0 + 64, N);
    if (n0 >= N) return;
    int g0 = batch[n0];
    int g1 = batch[n1 - 1];
    int range = g1 - g0 + 1;
    for (int i = threadIdx.x; i < range * FF; i += 256) acc[i] = 0.f;
    __syncthreads();
    int rows = n1 - n0;
    for (int idx = threadIdx.x; idx < rows * FF; idx += 256) {
        int r = idx / FF, c = idx % FF;
        int n = n0 + r;
        gAtomicAdd(&acc[(batch[n] - g0) * FF + c], h[n * FF + c]);
    }
    __syncthreads();
    for (int i = threadIdx.x; i < range * FF; i += 256) gAtomicAdd(&g[g0 * FF + i], acc[i]);
}

__global__ void mlp_kernel(const float* __restrict__ g,
                           const float* __restrict__ w1, const float* __restrict__ b1,
                           const float* __restrict__ w2, const float* __restrict__ b2,
                           const float* __restrict__ w3, const float* __restrict__ b3,
                           float* __restrict__ out) {
    __shared__ float gr[FF], h1[50], h2[25];
    int gi = blockIdx.x, t = threadIdx.x;
    for (int j = t; j < FF; j += 64) gr[j] = g[gi * FF + j];
    __syncthreads();
    if (t < 50) {
        float a = b1[t];
        for (int k = 0; k < FF; k++) a += gr[k] * w1[k * 50 + t];
        h1[t] = fmaxf(a, 0.f);
    }
    __syncthreads();
    if (t < 25) {
        float a = b2[t];
        for (int k = 0; k < 50; k++) a += h1[k] * w2[k * 25 + t];
        h2[t] = fmaxf(a, 0.f);
    }
    __syncthreads();
    if (t < 10) {
        float a = b3[t];
        for (int k = 0; k < 25; k++) a += h2[k] * w3[k * 10 + t];
        out[gi * 10 + t] = a;
    }
}

// ---------------- launch ----------------

extern "C" void kernel_launch(void* const* d_in, const int* in_sizes, int n_in,
                              void* d_out, int out_size, void* d_ws, size_t ws_size,
                              hipStream_t stream) {
    const float* x = (const float*)d_in[0];
    const int* ei = (const int*)d_in[1];
    const int* batch = (const int*)d_in[2];
    const float* gcn_w = (const float*)d_in[3];
    const float* gcn_b = (const float*)d_in[4];
    const float* pre_w = (const float*)d_in[5];
    const float* pre_b = (const float*)d_in[6];
    const float* post_w = (const float*)d_in[7];
    const float* lin_w = (const float*)d_in[9];
    const float* bn_g = (const float*)d_in[11];
    const float* bn_b = (const float*)d_in[12];
    const float* w1 = (const float*)d_in[13];
    const float* b1 = (const float*)d_in[14];
    const float* w2 = (const float*)d_in[15];
    const float* b2 = (const float*)d_in[16];
    const float* w3 = (const float*)d_in[17];
    const float* b3 = (const float*)d_in[18];
    float* out = (float*)d_out;

    const int* row = ei;
    const int* col = ei + EE;

    char* ws = (char*)d_ws;
    size_t off = 0;
    auto alloc = [&](size_t bytes) {
        char* p = ws + off;
        off += (bytes + 255) & ~(size_t)255;
        return p;
    };
    int* cnt = (int*)alloc(NN * 4);
    int* offs = (int*)alloc((NN + 1) * 4);
    int* cursor = (int*)alloc(NN * 4);
    int* csr = (int*)alloc(EE * 4);
    int* bsum = (int*)alloc(128 * 4);
    int* bbase = (int*)alloc(128 * 4);
    float* dinv = (float*)alloc(NN * 4);
    float* amp = (float*)alloc(NN * 4);
    float* att = (float*)alloc(NN * 4);
    float* scal = (float*)alloc((1 + LL * 160) * 4);  // [0]=sum log; per-layer bnsum/bnssq
    float* h = (float*)alloc((size_t)NN * FF * 4);
    ushort* hb = (ushort*)alloc((size_t)NN * KUV * 2);
    ushort* hagg = (ushort*)alloc((size_t)NN * KPOST * 2);
    float* ubuf = (float*)alloc((size_t)NN * 80 * 4);
    ushort* vbuf = (ushort*)alloc((size_t)NN * 80 * 2);
    ushort* obuf = (ushort*)alloc((size_t)NN * 80 * 2);
    float* o2 = (float*)alloc((size_t)NN * 80 * 4);  // also xw scratch in setup
    ushort* BTuv = (ushort*)alloc((size_t)S_UV * 2);
    ushort* BTpost = (ushort*)alloc((size_t)S_POST * 2);
    ushort* BTlin = (ushort*)alloc((size_t)S_LIN * 2);
    float* gbuf = (float*)alloc(GG * FF * 4);

    hipMemsetAsync(cnt, 0, NN * 4, stream);
    hipMemsetAsync(scal, 0, (1 + LL * 160) * 4, stream);
    hipMemsetAsync(gbuf, 0, GG * FF * 4, stream);

    const int B = 256;
    const int NB = (NN + 255) / 256;  // 79
    count_kernel<<<(EE + B - 1) / B, B, 0, stream>>>(col, cnt, EE);
    dinv_kernel<<<NB, B, 0, stream>>>(cnt, dinv, scal, NN);
    partial_kernel<<<NB, B, 0, stream>>>(cnt, bsum, NN);
    scanb_kernel<<<1, 128, 0, stream>>>(bsum, bbase, offs, NB);
    offs_kernel<<<NB, B, 0, stream>>>(cnt, bbase, offs, cursor, NN);
    fill_kernel<<<(EE + B - 1) / B, B, 0, stream>>>(row, col, cursor, csr, EE);
    xw_kernel<<<(NN * FF + B - 1) / B, B, 0, stream>>>(x, gcn_w, o2, NN);
    gcn_kernel<<<NN, 96, 0, stream>>>(o2, dinv, offs, csr, gcn_b, cnt, scal, h, hb, hagg,
                                      amp, att, NN);
    {
        int tot = S_UV + S_POST + S_LIN;
        prep_bt_kernel<<<(tot + B - 1) / B, B, 0, stream>>>(pre_w, pre_b, post_w, lin_w,
                                                            BTuv, BTpost, BTlin);
    }

    const int GB = (NN + 63) / 64;  // 313
    for (int l = 0; l < LL; l++) {
        float* bnsum = scal + 1 + l * 160;
        float* bnssq = bnsum + 80;

        gemm_uv_kernel<<<dim3(GB, 2), 256, 0, stream>>>(hb, BTuv + (size_t)l * NUV * KUV,
                                                        ubuf, vbuf, NN);
        edge_agg_kernel<<<NN, 128, 0, stream>>>(ubuf, vbuf, offs, csr, cnt, hagg, NN);
        post_group_kernel<<<dim3(GB, 5), 256, 0, stream>>>(
            hagg, BTpost + (size_t)l * NPOST * KPOST, amp, att, obuf, NN);
        lin_bn_kernel<<<GB, 256, 0, stream>>>(obuf, BTlin + (size_t)l * 80 * KLIN,
                                              o2, bnsum, bnssq, NN);
        bn_kernel<<<(NN * FF + B - 1) / B, B, 0, stream>>>(o2, bnsum, bnssq, bn_g + l * FF,
                                                           bn_b + l * FF, h, hb, hagg, NN);
    }

    pool_kernel<<<(NN + 63) / 64, 256, 0, stream>>>(h, batch, gbuf, NN);
    mlp_kernel<<<GG, 64, 0, stream>>>(gbuf, w1, b1, w2, b2, w3, b3, out);
}